// Round 3
// baseline (259.945 us; speedup 1.0000x reference)
//
#include <hip/hip_runtime.h>

#define TT 100
#define HH 100
#define NL 5
#define NOUT 10
#define NG 400        // 4*H gate rows
#define CC 10         // timesteps per inter-layer handoff chunk
#define NC (TT / CC)  // chunks

typedef float v2f __attribute__((ext_vector_type(2)));

__device__ __forceinline__ float sigm(float x) { return 1.f / (1.f + __expf(-x)); }

// One block per layer, wavefront-pipelined over timestep chunks.
// Lane layout: tid<400 -> j = tid>>2 (element), g = tid&3 (gate), row = g*100+j.
// Whh row (100 floats = 50 v2f) lives in VGPRs for the whole kernel.
// Wih contribution precomputed per chunk into REGISTERS xgr[10] (reader==writer).
__launch_bounds__(512, 1)
__global__ void lstm_pipe_kernel(
    const float* __restrict__ input,   // [T, H]
    const float* __restrict__ Wih,     // [L, 4H, H]
    const float* __restrict__ Whh,     // [L, 4H, H]
    const float* __restrict__ bih,     // [L, 4H]
    const float* __restrict__ bhh,     // [L, 4H]
    const float* __restrict__ Wout,    // [OUT, H]
    const float* __restrict__ bout,    // [OUT]
    float* __restrict__ out,           // [T, OUT]
    int* __restrict__ flags,           // [L-1, NC] chunk-ready flags
    float* __restrict__ xstage)        // [L-1, T, H] inter-layer activations
{
  const int l = blockIdx.x;
  const int tid = threadIdx.x;
  const int j = tid >> 2;
  const int g = tid & 3;
  const int row = g * HH + j;  // gate-major weight row

  __shared__ __align__(16) float xch[CC * HH];   // input chunk
  __shared__ __align__(16) float och[CC * HH];   // output chunk (or h history, l==4)
  __shared__ __align__(16) float hbuf[2][HH];    // double-buffered h

  // ---- persistent: Whh row in VGPRs ----
  v2f uv[50];
  float bias = 0.f;
  if (tid < NG) {
    const v2f* ur = (const v2f*)(Whh + (size_t)l * NG * HH + (size_t)row * HH);
#pragma unroll
    for (int k = 0; k < 50; ++k) uv[k] = ur[k];
    bias = bih[l * NG + row] + bhh[l * NG + row];
  }
  const float4* wr = (const float4*)(Wih + (size_t)l * NG * HH + (size_t)row * HH);

  float c = 0.f;
  if (tid < HH) hbuf[0][tid] = 0.f;

  for (int ch = 0; ch < NC; ++ch) {
    // ---- acquire + load x chunk into LDS ----
    if (l == 0) {
      if (tid < CC * HH / 4)
        ((float4*)xch)[tid] = ((const float4*)(input + ch * CC * HH))[tid];
    } else {
      const int* fl = flags + (l - 1) * NC + ch;
      while (__hip_atomic_load(fl, __ATOMIC_ACQUIRE, __HIP_MEMORY_SCOPE_AGENT) == 0)
        __builtin_amdgcn_s_sleep(1);
      const float4* src =
          (const float4*)(xstage + ((size_t)(l - 1) * TT + (size_t)ch * CC) * HH);
      if (tid < CC * HH / 4) ((float4*)xch)[tid] = src[tid];
    }
    __syncthreads();

    // ---- preamble: xgr[s] = bias + Wih[row] . x[s]  (into registers) ----
    float xgr[CC];
    if (tid < NG) {
      v2f acc[2 * CC];
#pragma unroll
      for (int s = 0; s < 2 * CC; ++s) acc[s] = (v2f){0.f, 0.f};
#pragma unroll 5
      for (int k = 0; k < 25; ++k) {
        float4 w4 = wr[k];  // global, L2-resident after chunk 0
        v2f wA = {w4.x, w4.y}, wB = {w4.z, w4.w};
#pragma unroll
        for (int s = 0; s < CC; ++s) {
          float4 xv = ((const float4*)xch)[s * 25 + k];  // uniform -> broadcast
          v2f xA = {xv.x, xv.y}, xB = {xv.z, xv.w};
          acc[2 * s] = wA * xA + acc[2 * s];
          acc[2 * s + 1] = wB * xB + acc[2 * s + 1];
        }
      }
#pragma unroll
      for (int s = 0; s < CC; ++s) {
        v2f t = acc[2 * s] + acc[2 * s + 1];
        xgr[s] = bias + t.x + t.y;
      }
    }

    // ---- CC recurrent steps, ONE barrier each ----
#pragma unroll
    for (int s = 0; s < CC; ++s) {
      __syncthreads();  // hbuf[s&1] (and xch->xgr at s==0) ready
      if (tid < NG) {
        const float4* h4 = (const float4*)hbuf[s & 1];
        v2f a0 = {xgr[s], 0.f}, a1 = {0.f, 0.f}, a2 = {0.f, 0.f}, a3 = {0.f, 0.f};
#pragma unroll
        for (int k = 0; k < 25; ++k) {
          float4 hv = h4[k];  // uniform -> broadcast
          v2f hA = {hv.x, hv.y}, hB = {hv.z, hv.w};
          if (k & 1) {
            a2 = uv[2 * k] * hA + a2;
            a3 = uv[2 * k + 1] * hB + a3;
          } else {
            a0 = uv[2 * k] * hA + a0;
            a1 = uv[2 * k + 1] * hB + a1;
          }
        }
        v2f t = (a0 + a2) + (a1 + a3);
        float a = t.x + t.y;

        // branchless activation: gate 2 -> tanh = 2*sigm(2a)-1, else sigm(a)
        bool isg = (g == 2);
        float m = isg ? 2.f : 1.f;
        float sg = 1.f / (1.f + __expf(-m * a));
        float v = isg ? 2.f * sg - 1.f : sg;

        // quad gate exchange: lane g holds gate g
        float v1 = __shfl_xor(v, 1);
        float v2v = __shfl_xor(v, 2);
        float v3 = __shfl_xor(v1, 2);
        if (g == 0) {  // v=i, v1=f, v2v=g, v3=o
          c = v1 * c + v * v2v;
          float tc = 2.f / (1.f + __expf(-2.f * c)) - 1.f;
          float h = v3 * tc;
          hbuf[(s + 1) & 1][j] = h;
          och[s * HH + j] = (l < NL - 1) ? fmaxf(h, 0.f) : h;
        }
      }
    }
    __syncthreads();  // last step's och/hbuf writes visible

    if (l < NL - 1) {
      // ---- publish chunk: coalesced write + fence + flag ----
      float4* dst = (float4*)(xstage + ((size_t)l * TT + (size_t)ch * CC) * HH);
      if (tid < CC * HH / 4) dst[tid] = ((const float4*)och)[tid];
      __syncthreads();  // all waves' stores drained (vmcnt at barrier)
      if (tid == 0) {
        __threadfence();
        __hip_atomic_store(flags + l * NC + ch, 1, __ATOMIC_RELEASE,
                           __HIP_MEMORY_SCOPE_AGENT);
      }
    } else {
      // ---- batched output projection for the whole chunk ----
      // tid<400: p=tid>>2 -> (s=p/10, r=p%10), q=tid&3 quarter of the dot
      if (tid < NG) {
        int p = tid >> 2, q = tid & 3;
        int s2 = p / 10, r = p % 10;
        const float* wrow = Wout + r * HH + q * 25;
        const float* hrow = och + s2 * HH + q * 25;
        float acc = 0.f;
#pragma unroll
        for (int m2 = 0; m2 < 25; ++m2) acc = fmaf(wrow[m2], hrow[m2], acc);
        acc += __shfl_xor(acc, 1);
        acc += __shfl_xor(acc, 2);
        if (q == 0) out[(ch * CC + s2) * NOUT + r] = sigm(acc + bout[r]);
      }
      __syncthreads();
    }
  }
}

extern "C" void kernel_launch(void* const* d_in, const int* in_sizes, int n_in,
                              void* d_out, int out_size, void* d_ws, size_t ws_size,
                              hipStream_t stream) {
  const float* input = (const float*)d_in[0];
  const float* Wih   = (const float*)d_in[1];
  const float* Whh   = (const float*)d_in[2];
  const float* bih   = (const float*)d_in[3];
  const float* bhh   = (const float*)d_in[4];
  const float* Wout  = (const float*)d_in[5];
  const float* bout  = (const float*)d_in[6];
  float* out = (float*)d_out;

  // workspace: [0,2048) flags ((L-1)*NC = 40 ints used),
  //            [2048, 2048+160000) xstage (4*100*100 floats)
  int* flags = (int*)d_ws;
  float* xstage = (float*)((char*)d_ws + 2048);

  // flags must be zero at kernel start on EVERY call (graph replays included)
  hipMemsetAsync(d_ws, 0, 2048, stream);

  lstm_pipe_kernel<<<dim3(NL), dim3(512), 0, stream>>>(
      input, Wih, Whh, bih, bhh, Wout, bout, out, flags, xstage);
}

// Round 4
// 207.615 us; speedup vs baseline: 1.2521x; 1.2521x over previous
//
#include <hip/hip_runtime.h>

#define TT 100
#define HH 100
#define NL 5
#define NOUT 10
#define NG 400        // 4*H gate rows
#define CC 10         // timesteps per inter-layer handoff chunk
#define NC (TT / CC)  // chunks

typedef float v2f __attribute__((ext_vector_type(2)));

__device__ __forceinline__ float sigm(float x) { return 1.f / (1.f + __expf(-x)); }

#define RPT25(M) M(0) M(1) M(2) M(3) M(4) M(5) M(6) M(7) M(8) M(9) M(10) M(11) \
                 M(12) M(13) M(14) M(15) M(16) M(17) M(18) M(19) M(20) M(21) M(22) M(23) M(24)

// One block per layer, wavefront-pipelined over timestep chunks.
// Lane layout: tid<400 -> j = tid>>2 (element), g = tid&3 (gate), row = g*100+j.
// BOTH weight rows (Wih row + Whh row = 200 floats) live in NAMED v2f registers:
// no local arrays on the hot path (R2/R3 showed the allocator never promotes them).
__launch_bounds__(512, 2)
__global__ void lstm_pipe_kernel(
    const float* __restrict__ input,   // [T, H]
    const float* __restrict__ Wih,     // [L, 4H, H]
    const float* __restrict__ Whh,     // [L, 4H, H]
    const float* __restrict__ bih,     // [L, 4H]
    const float* __restrict__ bhh,     // [L, 4H]
    const float* __restrict__ Wout,    // [OUT, H]
    const float* __restrict__ bout,    // [OUT]
    float* __restrict__ out,           // [T, OUT]
    int* __restrict__ flags,           // [L-1, NC] chunk-ready flags
    float* __restrict__ xstage)        // [L-1, T, H] inter-layer activations
{
  const int l = blockIdx.x;
  const int tid = threadIdx.x;
  const int j = tid >> 2;
  const int g = tid & 3;
  const int row = g * HH + j;  // gate-major weight row

  __shared__ __align__(16) float xch[CC * HH];  // input chunk
  __shared__ __align__(16) float och[CC * HH];  // output chunk / h history (l==4)
  __shared__ __align__(16) float hbuf[2][HH];   // double-buffered h

  // ---- 100 named v2f weight registers per lane ----
#define DECLW(k) v2f wA##k, wB##k, uA##k, uB##k;
  RPT25(DECLW)
  float bias = 0.f;
  if (tid < NG) {
    const float4* wr = (const float4*)(Wih + (size_t)l * NG * HH + (size_t)row * HH);
    const float4* ur = (const float4*)(Whh + (size_t)l * NG * HH + (size_t)row * HH);
#define LOADW(k)                                                         \
  {                                                                      \
    float4 t0 = wr[k];                                                   \
    wA##k = (v2f){t0.x, t0.y}; wB##k = (v2f){t0.z, t0.w};                \
    float4 t1 = ur[k];                                                   \
    uA##k = (v2f){t1.x, t1.y}; uB##k = (v2f){t1.z, t1.w};                \
  }
    RPT25(LOADW)
    bias = bih[l * NG + row] + bhh[l * NG + row];
  }

  float c = 0.f;                  // cell state, lane g==0 of quad j owns c[j]
  if (tid < HH) hbuf[0][tid] = 0.f;

  for (int ch = 0; ch < NC; ++ch) {
    // ---- acquire + load x chunk into LDS ----
    if (l == 0) {
      if (tid < CC * HH / 4)
        ((float4*)xch)[tid] = ((const float4*)(input + ch * CC * HH))[tid];
    } else {
      if (tid == 0) {
        const int* fl = flags + (l - 1) * NC + ch;
        while (__hip_atomic_load(fl, __ATOMIC_ACQUIRE, __HIP_MEMORY_SCOPE_AGENT) == 0)
          __builtin_amdgcn_s_sleep(1);
      }
      __syncthreads();  // flag seen -> chunk data visible (first-touch lines)
      const float4* src =
          (const float4*)(xstage + ((size_t)(l - 1) * TT + (size_t)ch * CC) * HH);
      if (tid < CC * HH / 4) ((float4*)xch)[tid] = src[tid];
    }

    // ---- CC recurrent steps, ONE barrier each ----
#pragma unroll 2
    for (int s = 0; s < CC; ++s) {
      __syncthreads();  // xch ready (s==0) / hbuf[s&1] ready
      if (tid < NG) {
        const float4* h4 = (const float4*)hbuf[s & 1];
        const float4* x4 = (const float4*)(xch + s * HH);
        v2f p0 = {bias, 0.f}, p1 = {0.f, 0.f}, p2 = {0.f, 0.f}, p3 = {0.f, 0.f};
        v2f q0 = {0.f, 0.f}, q1 = {0.f, 0.f}, q2 = {0.f, 0.f}, q3 = {0.f, 0.f};
#define FMAK(k)                                                             \
  {                                                                         \
    float4 hv = h4[k];                                                      \
    float4 xv = x4[k];                                                      \
    if ((k) & 1) {                                                          \
      p0 = uA##k * (v2f){hv.x, hv.y} + p0;                                  \
      p1 = uB##k * (v2f){hv.z, hv.w} + p1;                                  \
      p2 = wA##k * (v2f){xv.x, xv.y} + p2;                                  \
      p3 = wB##k * (v2f){xv.z, xv.w} + p3;                                  \
    } else {                                                                \
      q0 = uA##k * (v2f){hv.x, hv.y} + q0;                                  \
      q1 = uB##k * (v2f){hv.z, hv.w} + q1;                                  \
      q2 = wA##k * (v2f){xv.x, xv.y} + q2;                                  \
      q3 = wB##k * (v2f){xv.z, xv.w} + q3;                                  \
    }                                                                       \
  }
        RPT25(FMAK)
        v2f tsum = ((p0 + p1) + (p2 + p3)) + ((q0 + q1) + (q2 + q3));
        float a = tsum.x + tsum.y;

        // branchless activation: gate 2 -> tanh = 2*sigm(2a)-1, else sigm(a)
        bool isg = (g == 2);
        float m = isg ? 2.f : 1.f;
        float sg = 1.f / (1.f + __expf(-m * a));
        float v = isg ? 2.f * sg - 1.f : sg;

        // quad gate exchange: lane g holds gate g (i,f,g,o)
        float v1 = __shfl_xor(v, 1);
        float v2v = __shfl_xor(v, 2);
        float v3 = __shfl_xor(v1, 2);
        if (g == 0) {  // v=i, v1=f, v2v=g~, v3=o
          c = v1 * c + v * v2v;
          float tc = 2.f / (1.f + __expf(-2.f * c)) - 1.f;
          float h = v3 * tc;
          hbuf[(s + 1) & 1][j] = h;
          och[s * HH + j] = (l < NL - 1) ? fmaxf(h, 0.f) : h;
        }
      }
    }
    __syncthreads();  // last step's och writes visible to all lanes

    if (l < NL - 1) {
      // ---- publish chunk: coalesced write + fence + flag ----
      float4* dst = (float4*)(xstage + ((size_t)l * TT + (size_t)ch * CC) * HH);
      if (tid < CC * HH / 4) dst[tid] = ((const float4*)och)[tid];
      __syncthreads();  // all waves' global stores drained
      if (tid == 0) {
        __threadfence();
        __hip_atomic_store(flags + l * NC + ch, 1, __ATOMIC_RELEASE,
                           __HIP_MEMORY_SCOPE_AGENT);
      }
    } else {
      // ---- batched output projection for the whole chunk ----
      // tid<400: p=tid>>2 -> (s2=p/10, r=p%10), q=tid&3 quarter of the dot
      if (tid < NG) {
        int p = tid >> 2, q = tid & 3;
        int s2 = p / 10, r = p % 10;
        const float* wrow = Wout + r * HH + q * 25;
        const float* hrow = och + s2 * HH + q * 25;
        float acc = 0.f;
#pragma unroll
        for (int m2 = 0; m2 < 25; ++m2) acc = fmaf(wrow[m2], hrow[m2], acc);
        acc += __shfl_xor(acc, 1);
        acc += __shfl_xor(acc, 2);
        if (q == 0) out[(ch * CC + s2) * NOUT + r] = sigm(acc + bout[r]);
      }
    }
  }
}

extern "C" void kernel_launch(void* const* d_in, const int* in_sizes, int n_in,
                              void* d_out, int out_size, void* d_ws, size_t ws_size,
                              hipStream_t stream) {
  const float* input = (const float*)d_in[0];
  const float* Wih   = (const float*)d_in[1];
  const float* Whh   = (const float*)d_in[2];
  const float* bih   = (const float*)d_in[3];
  const float* bhh   = (const float*)d_in[4];
  const float* Wout  = (const float*)d_in[5];
  const float* bout  = (const float*)d_in[6];
  float* out = (float*)d_out;

  // workspace: [0,2048) flags ((L-1)*NC = 40 ints used),
  //            [2048, 2048+160000) xstage (4*100*100 floats)
  int* flags = (int*)d_ws;
  float* xstage = (float*)((char*)d_ws + 2048);

  // flags must be zero at kernel start on EVERY call (graph replays included)
  hipMemsetAsync(d_ws, 0, 2048, stream);

  lstm_pipe_kernel<<<dim3(NL), dim3(512), 0, stream>>>(
      input, Wih, Whh, bih, bhh, Wout, bout, out, flags, xstage);
}